// Round 8
// baseline (87.053 us; speedup 1.0000x reference)
//
#include <hip/hip_runtime.h>

#define BB 8
#define CC 80
#define HH 128
#define WWW 128
#define KK 32

constexpr int HWc  = HH * WWW;      // 16384
constexpr int CHWc = CC * HWc;      // 1310720
constexpr float RESf   = 1e-4f;
constexpr float PULL_W = 0.1f;
constexpr float PUSH_W = 0.1f;
constexpr float OFF_W  = 1.0f;
constexpr float XCLAMP = 9.210240f; // ln(9999): sigmoid(±XCLAMP) = 1-1e-4 / 1e-4

// ws layout (floats):
// [0..B) tl focal | [B..2B) tl npos | [2B..3B) br focal | [3B..4B) br npos
// [4B..5B) tl offset | [5B..6B) br offset
// [6B .. 6B+B*(K+1)) tl_list | [+B*(K+1)) br_list
constexpr int WS_FLOATS = 6 * BB + 2 * BB * (KK + 1);

__device__ __forceinline__ void waveReduce2(float& a, float& b) {
#pragma unroll
    for (int off = 32; off; off >>= 1) {
        a += __shfl_down(a, off);
        b += __shfl_down(b, off);
    }
}

__device__ __forceinline__ float waveReduce1(float a) {
#pragma unroll
    for (int off = 32; off; off >>= 1) a += __shfl_down(a, off);
    return a;
}

// R8: flat block-contiguous geometry (m13/m146-style single stream).
// grid (1280, 2): block r owns contiguous 2048 float4 (32 KB) per stream:
//   i4 = r*2048 + it*256 + tid, it = 0..7.
// 160 blocks per batch exactly -> batch b = r/160 is wave-uniform, so the
// per-batch reduction stays at 2 atomics/block (why R1-R7 sliced the grid).
// R1-R7 post-mortem: load mechanism (implicit / asm-pinned / DMA), per-wave
// MLP, and occupancy all null at ~2.5 TB/s; geometry is the last variable.
__global__ __launch_bounds__(256) void focal_kernel(
    const float* __restrict__ tl, const float* __restrict__ gtl,
    const float* __restrict__ br, const float* __restrict__ gbr,
    float* __restrict__ ws) {
    const int r = blockIdx.x;            // 0..1279
    const int z = blockIdx.y;            // 0: tl, 1: br
    const int b = r / 160;               // wave-uniform batch
    const float4* pr4 = (const float4*)(z ? br : tl);
    const float4* gt4 = (const float4*)(z ? gbr : gtl);
    float* lsum = ws + z * 2 * BB;
    float* npos = lsum + BB;

    const int base = r * 2048 + threadIdx.x;

    float ls = 0.f, np = 0.f;
#pragma unroll
    for (int it = 0; it < 8; ++it) {
        const int i4 = base + it * 256;
        float4 xv = pr4[i4];
        float4 gv = gt4[i4];
        float xs[4] = {xv.x, xv.y, xv.z, xv.w};
        float gs[4] = {gv.x, gv.y, gv.z, gv.w};
#pragma unroll
        for (int j = 0; j < 4; ++j) {
            float x = xs[j], g = gs[j];
            // clamp x <=> clip(sigmoid(x), 1e-4, 1-1e-4)
            float xc = fminf(fmaxf(x, -XCLAMP), XCLAMP);
            float e = __expf(xc);
            float rr = __builtin_amdgcn_rcpf(1.f + e); // rr = 1-p exactly
            float p = e * rr;
            float logq = __logf(rr);     // log(1-p)
            float logp = xc + logq;      // log(p)
            bool pos = (g == 1.0f);
            float om = 1.f - g;
            float om2 = om * om;
            float v = pos ? rr * rr * logp
                          : om2 * om2 * p * p * logq;
            ls += v;
            np += pos ? 1.f : 0.f;
        }
    }

    waveReduce2(ls, np);
    __shared__ float sl[4], sn[4];
    const int wid = threadIdx.x >> 6;
    if ((threadIdx.x & 63) == 0) { sl[wid] = ls; sn[wid] = np; }
    __syncthreads();
    if (threadIdx.x == 0) {
        atomicAdd(&lsum[b], sl[0] + sl[1] + sl[2] + sl[3]);
        atomicAdd(&npos[b], sn[0] + sn[1] + sn[2] + sn[3]);
    }
}

__global__ __launch_bounds__(256) void offset_kernel(
    const float* __restrict__ tlo, const float* __restrict__ gtlo,
    const float* __restrict__ bro, const float* __restrict__ gbro,
    const int* __restrict__ tpos, const int* __restrict__ bpos,
    float* __restrict__ ws) {
    const int b = blockIdx.y, z = blockIdx.z;
    const float* pr = (z ? bro : tlo) + (size_t)b * 2 * HWc;
    const float* gt = (z ? gbro : gtlo) + (size_t)b * 2 * HWc;
    const int* pos = (z ? bpos : tpos) + (size_t)b * HWc;

    const float4* pr4 = (const float4*)pr;
    const float4* gt4 = (const float4*)gt;
    const int4*  pos4 = (const int4*)pos;
    const int n4 = 2 * HWc / 4;          // 8192
    const int hw4n = HWc / 4;            // 4096 (pow2)

    float s = 0.f;
    for (int i = blockIdx.x * blockDim.x + threadIdx.x; i < n4;
         i += gridDim.x * blockDim.x) {
        int hw4 = i & (hw4n - 1);
        float4 pv = pr4[i], gv = gt4[i];
        int4 pp = pos4[hw4];
        float ps[4] = {pv.x, pv.y, pv.z, pv.w};
        float gs[4] = {gv.x, gv.y, gv.z, gv.w};
        int ms[4] = {pp.x, pp.y, pp.z, pp.w};
#pragma unroll
        for (int j = 0; j < 4; ++j) {
            float d = fabsf(ps[j] - gs[j]);
            float l = (d < 1.f) ? 0.5f * d * d : d - 0.5f;
            s += (ms[j] != 0) ? l : 0.f;
        }
    }
    s = waveReduce1(s);
    __shared__ float sm[4];
    if ((threadIdx.x & 63) == 0) sm[threadIdx.x >> 6] = s;
    __syncthreads();
    if (threadIdx.x == 0)
        atomicAdd(&ws[4 * BB + z * BB + b], sm[0] + sm[1] + sm[2] + sm[3]);
}

__global__ __launch_bounds__(256) void gather_kernel(
    const float* __restrict__ tle, const float* __restrict__ bre,
    const int* __restrict__ tpos, const int* __restrict__ bpos,
    float* __restrict__ ws) {
    const int b = blockIdx.y, z = blockIdx.z;
    const float* e = (z ? bre : tle) + (size_t)b * HWc;
    const int* pos = (z ? bpos : tpos) + (size_t)b * HWc;
    float* list = ws + 6 * BB + z * BB * (KK + 1) + b * (KK + 1);
    const int n4 = HWc / 4;              // 4096
    for (int i = blockIdx.x * blockDim.x + threadIdx.x; i < n4;
         i += gridDim.x * blockDim.x) {
        float4 ev = ((const float4*)e)[i];
        int4 pv = ((const int4*)pos)[i];
        if (pv.x) atomicAdd(&list[pv.x], ev.x);
        if (pv.y) atomicAdd(&list[pv.y], ev.y);
        if (pv.z) atomicAdd(&list[pv.z], ev.z);
        if (pv.w) atomicAdd(&list[pv.w], ev.w);
    }
}

__global__ __launch_bounds__(256) void final_kernel(
    const float* __restrict__ ws, const int* __restrict__ gt_obj_mask,
    float* __restrict__ out) {
    __shared__ float tls[BB * (KK + 1)], brs[BB * (KK + 1)], mns[BB * (KK + 1)];
    __shared__ float objf[BB];
    const int t = threadIdx.x;
    if (t < BB) objf[t] = (float)gt_obj_mask[t];
    const float* wtl = ws + 6 * BB;
    const float* wbr = wtl + BB * (KK + 1);
    for (int i = t; i < BB * (KK + 1); i += blockDim.x) {
        int k = i % (KK + 1);
        float a = (k == 0) ? 0.f : wtl[i];
        float c = (k == 0) ? 0.f : wbr[i];
        tls[i] = a; brs[i] = c; mns[i] = 0.5f * (a + c);
    }
    __syncthreads();

    float acc = 0.f;
    // pull
    for (int i = t; i < BB * (KK + 1); i += blockDim.x) {
        int b = i / (KK + 1);
        float m = mns[i];
        float d1 = tls[i] - m, d2 = brs[i] - m;
        acc += PULL_W * (d1 * d1 + d2 * d2) / (objf[b] + RESf);
    }
    // push: D_ij = relu(1-|m_i-m_j|), i,j in [1..K]
    for (int i = t; i < BB * KK * KK; i += blockDim.x) {
        int b = i / (KK * KK);
        int r = i % (KK * KK);
        int ii = r / KK, jj = r % KK;
        float mi = mns[b * (KK + 1) + 1 + ii];
        float mj = mns[b * (KK + 1) + 1 + jj];
        float d = 1.f - fabsf(mi - mj);
        float D = d > 0.f ? d : 0.f;
        acc += PUSH_W * D / (objf[b] * (objf[b] - 1.f) + RESf);
    }
    // per-batch scalar terms
    for (int b = t; b < BB; b += blockDim.x) {
        float of = objf[b];
        acc += -(ws[b]) / ws[BB + b];                 // tl focal
        acc += -(ws[2 * BB + b]) / ws[3 * BB + b];    // br focal
        acc += OFF_W * ws[4 * BB + b] / (of + RESf);  // tl offset
        acc += OFF_W * ws[5 * BB + b] / (of + RESf);  // br offset
        acc += -PUSH_W * of / (of * (of - 1.f) + RESf); // "- objf" in dist
    }

    acc = waveReduce1(acc);
    __shared__ float sa[4];
    if ((t & 63) == 0) sa[t >> 6] = acc;
    __syncthreads();
    if (t == 0) out[0] = (sa[0] + sa[1] + sa[2] + sa[3]) / (float)BB;
}

extern "C" void kernel_launch(void* const* d_in, const int* in_sizes, int n_in,
                              void* d_out, int out_size, void* d_ws, size_t ws_size,
                              hipStream_t stream) {
    const float* tl_heats      = (const float*)d_in[0];
    const float* tl_embeds     = (const float*)d_in[1];
    const float* tl_offsets    = (const float*)d_in[2];
    const float* br_heats      = (const float*)d_in[3];
    const float* br_embeds     = (const float*)d_in[4];
    const float* br_offsets    = (const float*)d_in[5];
    const float* gt_tl_heats   = (const float*)d_in[6];
    const float* gt_br_heats   = (const float*)d_in[7];
    const float* gt_tl_offsets = (const float*)d_in[8];
    const float* gt_br_offsets = (const float*)d_in[9];
    const int*   gt_tl_pos     = (const int*)d_in[10];
    const int*   gt_br_pos     = (const int*)d_in[11];
    const int*   gt_obj_mask   = (const int*)d_in[12];
    float* out = (float*)d_out;
    float* ws  = (float*)d_ws;

    hipMemsetAsync(ws, 0, WS_FLOATS * sizeof(float), stream);

    focal_kernel<<<dim3(1280, 2), 256, 0, stream>>>(
        tl_heats, gt_tl_heats, br_heats, gt_br_heats, ws);
    offset_kernel<<<dim3(8, BB, 2), 256, 0, stream>>>(
        tl_offsets, gt_tl_offsets, br_offsets, gt_br_offsets,
        gt_tl_pos, gt_br_pos, ws);
    gather_kernel<<<dim3(4, BB, 2), 256, 0, stream>>>(
        tl_embeds, br_embeds, gt_tl_pos, gt_br_pos, ws);
    final_kernel<<<1, 256, 0, stream>>>(ws, gt_obj_mask, out);
}

// Round 9
// 59.077 us; speedup vs baseline: 1.4736x; 1.4736x over previous
//
#include <hip/hip_runtime.h>

#define BB 8
#define CC 80
#define HH 128
#define WWW 128
#define KK 32

constexpr int HWc  = HH * WWW;      // 16384
constexpr int CHWc = CC * HWc;      // 1310720
constexpr float RESf   = 1e-4f;
constexpr float PULL_W = 0.1f;
constexpr float PUSH_W = 0.1f;
constexpr float OFF_W  = 1.0f;
constexpr float XCLAMP = 9.210240f; // ln(9999): sigmoid(±XCLAMP) = 1-1e-4 / 1e-4

typedef float f32x4 __attribute__((ext_vector_type(4)));

// ws layout (floats):
// [0..B) tl focal | [B..2B) tl npos | [2B..3B) br focal | [3B..4B) br npos
// [4B..5B) tl offset | [5B..6B) br offset
// [6B .. 6B+B*(K+1)) tl_list | [+B*(K+1)) br_list
constexpr int WS_FLOATS = 6 * BB + 2 * BB * (KK + 1);

__device__ __forceinline__ void waveReduce2(float& a, float& b) {
#pragma unroll
    for (int off = 32; off; off >>= 1) {
        a += __shfl_down(a, off);
        b += __shfl_down(b, off);
    }
}

__device__ __forceinline__ float waveReduce1(float a) {
#pragma unroll
    for (int off = 32; off; off >>= 1) a += __shfl_down(a, off);
    return a;
}

// R9: R2's structure (best measured: 64x8x2 grid, U=4, MACRO=5) with
// NON-TEMPORAL loads. R1-R8 matrix: mechanism/MLP/occupancy/geometry all
// null at ~2.5 TB/s -> only untested variable is L2/L3 allocation policy
// for the 168 MB zero-reuse stream (FETCH_SIZE stuck at exactly half the
// footprint every replay). nt = evict-first streaming hint.
__global__ __launch_bounds__(256) void focal_kernel(
    const float* __restrict__ tl, const float* __restrict__ gtl,
    const float* __restrict__ br, const float* __restrict__ gbr,
    float* __restrict__ ws) {
    const int b = blockIdx.y;
    const int z = blockIdx.z;
    const f32x4* lg4 = (const f32x4*)((z ? br : tl) + (size_t)b * CHWc);
    const f32x4* gt4 = (const f32x4*)((z ? gbr : gtl) + (size_t)b * CHWc);
    float* lsum = ws + z * 2 * BB;
    float* npos = lsum + BB;

    constexpr int S = 64 * 256;               // 16384 threads in x
    constexpr int U = 4;
    constexpr int MACRO = CHWc / 4 / (U * S); // 5
    const int tid = blockIdx.x * 256 + threadIdx.x;

    float ls = 0.f, np = 0.f;
#pragma unroll 1
    for (int m = 0; m < MACRO; ++m) {
        const int base = m * U * S + tid;
        f32x4 xv[U], gv[U];
#pragma unroll
        for (int u = 0; u < U; ++u) {
            xv[u] = __builtin_nontemporal_load(lg4 + base + u * S);
            gv[u] = __builtin_nontemporal_load(gt4 + base + u * S);
        }
#pragma unroll
        for (int u = 0; u < U; ++u) {
#pragma unroll
            for (int j = 0; j < 4; ++j) {
                float x = xv[u][j], g = gv[u][j];
                // clamp x <=> clip(sigmoid(x), 1e-4, 1-1e-4)
                float xc = fminf(fmaxf(x, -XCLAMP), XCLAMP);
                float e = __expf(xc);
                float r = __builtin_amdgcn_rcpf(1.f + e); // r = 1-p exactly
                float p = e * r;
                float logq = __logf(r);      // log(1-p)
                float logp = xc + logq;      // log(p)
                bool pos = (g == 1.0f);
                float om = 1.f - g;
                float om2 = om * om;
                float v = pos ? r * r * logp
                              : om2 * om2 * p * p * logq;
                ls += v;
                np += pos ? 1.f : 0.f;
            }
        }
    }
    waveReduce2(ls, np);
    __shared__ float sl[4], sn[4];
    const int wid = threadIdx.x >> 6;
    if ((threadIdx.x & 63) == 0) { sl[wid] = ls; sn[wid] = np; }
    __syncthreads();
    if (threadIdx.x == 0) {
        atomicAdd(&lsum[b], sl[0] + sl[1] + sl[2] + sl[3]);
        atomicAdd(&npos[b], sn[0] + sn[1] + sn[2] + sn[3]);
    }
}

__global__ __launch_bounds__(256) void offset_kernel(
    const float* __restrict__ tlo, const float* __restrict__ gtlo,
    const float* __restrict__ bro, const float* __restrict__ gbro,
    const int* __restrict__ tpos, const int* __restrict__ bpos,
    float* __restrict__ ws) {
    const int b = blockIdx.y, z = blockIdx.z;
    const float* pr = (z ? bro : tlo) + (size_t)b * 2 * HWc;
    const float* gt = (z ? gbro : gtlo) + (size_t)b * 2 * HWc;
    const int* pos = (z ? bpos : tpos) + (size_t)b * HWc;

    const float4* pr4 = (const float4*)pr;
    const float4* gt4 = (const float4*)gt;
    const int4*  pos4 = (const int4*)pos;
    const int n4 = 2 * HWc / 4;          // 8192
    const int hw4n = HWc / 4;            // 4096 (pow2)

    float s = 0.f;
    for (int i = blockIdx.x * blockDim.x + threadIdx.x; i < n4;
         i += gridDim.x * blockDim.x) {
        int hw4 = i & (hw4n - 1);
        float4 pv = pr4[i], gv = gt4[i];
        int4 pp = pos4[hw4];
        float ps[4] = {pv.x, pv.y, pv.z, pv.w};
        float gs[4] = {gv.x, gv.y, gv.z, gv.w};
        int ms[4] = {pp.x, pp.y, pp.z, pp.w};
#pragma unroll
        for (int j = 0; j < 4; ++j) {
            float d = fabsf(ps[j] - gs[j]);
            float l = (d < 1.f) ? 0.5f * d * d : d - 0.5f;
            s += (ms[j] != 0) ? l : 0.f;
        }
    }
    s = waveReduce1(s);
    __shared__ float sm[4];
    if ((threadIdx.x & 63) == 0) sm[threadIdx.x >> 6] = s;
    __syncthreads();
    if (threadIdx.x == 0)
        atomicAdd(&ws[4 * BB + z * BB + b], sm[0] + sm[1] + sm[2] + sm[3]);
}

__global__ __launch_bounds__(256) void gather_kernel(
    const float* __restrict__ tle, const float* __restrict__ bre,
    const int* __restrict__ tpos, const int* __restrict__ bpos,
    float* __restrict__ ws) {
    const int b = blockIdx.y, z = blockIdx.z;
    const float* e = (z ? bre : tle) + (size_t)b * HWc;
    const int* pos = (z ? bpos : tpos) + (size_t)b * HWc;
    float* list = ws + 6 * BB + z * BB * (KK + 1) + b * (KK + 1);
    const int n4 = HWc / 4;              // 4096
    for (int i = blockIdx.x * blockDim.x + threadIdx.x; i < n4;
         i += gridDim.x * blockDim.x) {
        float4 ev = ((const float4*)e)[i];
        int4 pv = ((const int4*)pos)[i];
        if (pv.x) atomicAdd(&list[pv.x], ev.x);
        if (pv.y) atomicAdd(&list[pv.y], ev.y);
        if (pv.z) atomicAdd(&list[pv.z], ev.z);
        if (pv.w) atomicAdd(&list[pv.w], ev.w);
    }
}

__global__ __launch_bounds__(256) void final_kernel(
    const float* __restrict__ ws, const int* __restrict__ gt_obj_mask,
    float* __restrict__ out) {
    __shared__ float tls[BB * (KK + 1)], brs[BB * (KK + 1)], mns[BB * (KK + 1)];
    __shared__ float objf[BB];
    const int t = threadIdx.x;
    if (t < BB) objf[t] = (float)gt_obj_mask[t];
    const float* wtl = ws + 6 * BB;
    const float* wbr = wtl + BB * (KK + 1);
    for (int i = t; i < BB * (KK + 1); i += blockDim.x) {
        int k = i % (KK + 1);
        float a = (k == 0) ? 0.f : wtl[i];
        float c = (k == 0) ? 0.f : wbr[i];
        tls[i] = a; brs[i] = c; mns[i] = 0.5f * (a + c);
    }
    __syncthreads();

    float acc = 0.f;
    // pull
    for (int i = t; i < BB * (KK + 1); i += blockDim.x) {
        int b = i / (KK + 1);
        float m = mns[i];
        float d1 = tls[i] - m, d2 = brs[i] - m;
        acc += PULL_W * (d1 * d1 + d2 * d2) / (objf[b] + RESf);
    }
    // push: D_ij = relu(1-|m_i-m_j|), i,j in [1..K]
    for (int i = t; i < BB * KK * KK; i += blockDim.x) {
        int b = i / (KK * KK);
        int r = i % (KK * KK);
        int ii = r / KK, jj = r % KK;
        float mi = mns[b * (KK + 1) + 1 + ii];
        float mj = mns[b * (KK + 1) + 1 + jj];
        float d = 1.f - fabsf(mi - mj);
        float D = d > 0.f ? d : 0.f;
        acc += PUSH_W * D / (objf[b] * (objf[b] - 1.f) + RESf);
    }
    // per-batch scalar terms
    for (int b = t; b < BB; b += blockDim.x) {
        float of = objf[b];
        acc += -(ws[b]) / ws[BB + b];                 // tl focal
        acc += -(ws[2 * BB + b]) / ws[3 * BB + b];    // br focal
        acc += OFF_W * ws[4 * BB + b] / (of + RESf);  // tl offset
        acc += OFF_W * ws[5 * BB + b] / (of + RESf);  // br offset
        acc += -PUSH_W * of / (of * (of - 1.f) + RESf); // "- objf" in dist
    }

    acc = waveReduce1(acc);
    __shared__ float sa[4];
    if ((t & 63) == 0) sa[t >> 6] = acc;
    __syncthreads();
    if (t == 0) out[0] = (sa[0] + sa[1] + sa[2] + sa[3]) / (float)BB;
}

extern "C" void kernel_launch(void* const* d_in, const int* in_sizes, int n_in,
                              void* d_out, int out_size, void* d_ws, size_t ws_size,
                              hipStream_t stream) {
    const float* tl_heats      = (const float*)d_in[0];
    const float* tl_embeds     = (const float*)d_in[1];
    const float* tl_offsets    = (const float*)d_in[2];
    const float* br_heats      = (const float*)d_in[3];
    const float* br_embeds     = (const float*)d_in[4];
    const float* br_offsets    = (const float*)d_in[5];
    const float* gt_tl_heats   = (const float*)d_in[6];
    const float* gt_br_heats   = (const float*)d_in[7];
    const float* gt_tl_offsets = (const float*)d_in[8];
    const float* gt_br_offsets = (const float*)d_in[9];
    const int*   gt_tl_pos     = (const int*)d_in[10];
    const int*   gt_br_pos     = (const int*)d_in[11];
    const int*   gt_obj_mask   = (const int*)d_in[12];
    float* out = (float*)d_out;
    float* ws  = (float*)d_ws;

    hipMemsetAsync(ws, 0, WS_FLOATS * sizeof(float), stream);

    focal_kernel<<<dim3(64, BB, 2), 256, 0, stream>>>(
        tl_heats, gt_tl_heats, br_heats, gt_br_heats, ws);
    offset_kernel<<<dim3(8, BB, 2), 256, 0, stream>>>(
        tl_offsets, gt_tl_offsets, br_offsets, gt_br_offsets,
        gt_tl_pos, gt_br_pos, ws);
    gather_kernel<<<dim3(4, BB, 2), 256, 0, stream>>>(
        tl_embeds, br_embeds, gt_tl_pos, gt_br_pos, ws);
    final_kernel<<<1, 256, 0, stream>>>(ws, gt_obj_mask, out);
}